// Round 13
// baseline (109.481 us; speedup 1.0000x reference)
//
#include <hip/hip_runtime.h>
#include <hip/hip_bf16.h>

typedef __hip_bfloat16 bf16;
typedef __attribute__((ext_vector_type(8))) short short8;
typedef __attribute__((ext_vector_type(4))) short short4v;
typedef __attribute__((ext_vector_type(4))) float f32x4;
typedef __attribute__((ext_vector_type(4))) float float4v;

static __device__ inline short f2bf(float f){
  __hip_bfloat16 h = __float2bfloat16(f);
  return *reinterpret_cast<short*>(&h);
}

// single-instruction packed fp32->bf16 (RNE)
static __device__ __forceinline__ unsigned cvt_pk_bf16(float lo, float hi){
  unsigned r;
  asm("v_cvt_pk_bf16_f32 %0, %1, %2" : "=v"(r) : "v"(lo), "v"(hi));
  return r;
}

// raw hardware exp2
static __device__ __forceinline__ float exp2_fast(float x){
  float r;
  asm("v_exp_f32 %0, %1" : "=v"(r) : "v"(x));
  return r;
}

static __device__ __forceinline__ float max3f(float a, float b, float c){
  float r;
  asm("v_max3_f32 %0, %1, %2, %3" : "=v"(r) : "v"(a), "v"(b), "v"(c));
  return r;
}

static __device__ inline short8 load8(const float* p){
  float4v a = *reinterpret_cast<const float4v*>(p);
  float4v b = *reinterpret_cast<const float4v*>(p + 4);
  short8 r;
  unsigned* u = reinterpret_cast<unsigned*>(&r);
  u[0] = cvt_pk_bf16(a[0], a[1]);
  u[1] = cvt_pk_bf16(a[2], a[3]);
  u[2] = cvt_pk_bf16(b[0], b[1]);
  u[3] = cvt_pk_bf16(b[2], b[3]);
  return r;
}
static __device__ inline short8 load8(const bf16* p){
  return *reinterpret_cast<const short8*>(p);
}

// async global->LDS DMA, 16B/lane: lane i lands at lds + i*16B (wave-linear)
typedef __attribute__((address_space(1))) const unsigned int gas_u32;
typedef __attribute__((address_space(3))) unsigned int las_u32;
static __device__ __forceinline__ void gload16(const void* g, void* l){
  __builtin_amdgcn_global_load_lds((gas_u32*)g, (las_u32*)l, 16, 0, 0);
}

// counted-vmcnt wait + raw barrier + scheduling fence (rule 18)
template<int N>
static __device__ __forceinline__ void vm_barrier(){
  if constexpr (N == 8) asm volatile("s_waitcnt vmcnt(8)" ::: "memory");
  else if constexpr (N == 6) asm volatile("s_waitcnt vmcnt(6)" ::: "memory");
  else if constexpr (N == 4) asm volatile("s_waitcnt vmcnt(4)" ::: "memory");
  else asm volatile("s_waitcnt vmcnt(0)" ::: "memory");
  __builtin_amdgcn_s_barrier();
  __builtin_amdgcn_sched_barrier(0);
}

// weights-only fp32 -> bf16 prepass + rope cos/sin table
#define CW_WQ  0
#define CW_WK  1048576
#define CW_WV  1310720
#define CW_WO  1572864
#define CW_TOT 2621440
__global__ void cvt_kernel(bf16* __restrict__ dst, float* __restrict__ tab,
    const float* wq, const float* wk, const float* wv, const float* wo){
  if (blockIdx.x < 256){   // rope table: tab[s*32+d] = {cos,sin}(s*10000^(-d/32))
    const int idx = blockIdx.x * 256 + threadIdx.x;
    const int d = idx & 31, s = idx >> 5;
    const float ang = (float)s * exp2f(-0.41524101186092030f * (float)d);
    float sn, cs;
    sincosf(ang, &sn, &cs);
    tab[idx*2] = cs; tab[idx*2+1] = sn;
  }
  const size_t i8 = ((size_t)blockIdx.x * 256 + threadIdx.x) * 8;
  const float* src; size_t off;
  if      (i8 < CW_WK){ src = wq; off = i8; }
  else if (i8 < CW_WV){ src = wk; off = i8 - CW_WK; }
  else if (i8 < CW_WO){ src = wv; off = i8 - CW_WV; }
  else                { src = wo; off = i8 - CW_WO; }
  *reinterpret_cast<short8*>(reinterpret_cast<short*>(dst) + i8) = load8(src + off);
}

// ---------------- GEMM with fp32-A DMA staging (QKV projections) ----------
// C = A[M,K]fp32 @ B[N,K]^T bf16 + bias. 128x128 tile, BK=32, 3-buf rotation,
// stage AFTER barrier (race-free with 3 buffers), counted vmcnt(6).
// A staged raw fp32 (16KB/tile), converted to bf16 at fragment load.
template<int MODE>
__device__ __forceinline__ void gemm_f32a(
    char* lds, void* __restrict__ Cout,
    const float* __restrict__ A, const bf16* __restrict__ B,
    const float* __restrict__ bias, const float* __restrict__ tab,
    int ntile, int N, int K)
{
  const int NK = K >> 5;
  const int n0 = ntile * 128, m0 = blockIdx.y * 128;
  const int tid = threadIdx.x, w = tid >> 6, lane = tid & 63;
  const int wm = w >> 1, wn = w & 1, lr = lane & 15, lg = lane >> 4;
  // staging sources (pre-swizzled granule columns)
  const int l8 = lane >> 3, gA = lane & 7;          // A: 8 rows x 8 granules/row
  const float* Asrc[4];
  #pragma unroll
  for (int j = 0; j < 4; j++)
    Asrc[j] = A + (size_t)(m0 + w*32 + j*8 + l8) * K + ((gA ^ l8) * 4);
  const int s4 = lane >> 2, gB = lane & 3;          // B: 16 rows x 4 granules/row
  const bf16* Bsrc[2];
  #pragma unroll
  for (int j = 0; j < 2; j++)
    Bsrc[j] = B + (size_t)(n0 + w*32 + j*16 + s4) * K + ((gB ^ ((s4 >> 1) & 3)) * 8);
  // hoisted swizzled fragment read offsets
  const int swA = lr & 7, swB = (lr >> 1) & 3;
  int offAlo[4], offAhi[4], offB[4];
  #pragma unroll
  for (int i = 0; i < 4; i++){
    const int ra = wm*64 + i*16 + lr;
    offAlo[i] = ra*128 + ((2*lg)     ^ swA) * 16;
    offAhi[i] = ra*128 + ((2*lg + 1) ^ swA) * 16;
    const int rb = wn*64 + i*16 + lr;
    offB[i]   = rb*64  + ((lg ^ swB) * 16);
  }
  auto stage = [&](char* buf, int t){
    char* dA = buf + w*4096;
    char* dB = buf + 16384 + w*2048;
    #pragma unroll
    for (int j = 0; j < 4; j++) gload16(Asrc[j] + t*32, dA + j*1024);
    #pragma unroll
    for (int j = 0; j < 2; j++) gload16(Bsrc[j] + t*32, dB + j*1024);
  };
  char* b0 = lds;
  char* b1 = lds + 24576;
  char* b2 = lds + 49152;
  f32x4 acc[4][4] = {};
  stage(b0, 0); stage(b1, 1);
  for (int t = 0; t < NK; t++){
    if (t < NK-1) vm_barrier<6>(); else vm_barrier<0>();
    if (t + 2 < NK) stage(b2, t + 2);   // post-barrier: b2's readers are done
    short8 af[4], bfm[4];
    #pragma unroll
    for (int i = 0; i < 4; i++){
      float4v lo = *reinterpret_cast<const float4v*>(b0 + offAlo[i]);
      float4v hi = *reinterpret_cast<const float4v*>(b0 + offAhi[i]);
      unsigned* u = reinterpret_cast<unsigned*>(&af[i]);
      u[0] = cvt_pk_bf16(lo[0], lo[1]); u[1] = cvt_pk_bf16(lo[2], lo[3]);
      u[2] = cvt_pk_bf16(hi[0], hi[1]); u[3] = cvt_pk_bf16(hi[2], hi[3]);
    }
    #pragma unroll
    for (int i = 0; i < 4; i++)
      bfm[i] = *reinterpret_cast<const short8*>(b0 + 16384 + offB[i]);
    __builtin_amdgcn_s_setprio(1);
    #pragma unroll
    for (int mt = 0; mt < 4; mt++)
      #pragma unroll
      for (int nt = 0; nt < 4; nt++)
        acc[mt][nt] = __builtin_amdgcn_mfma_f32_16x16x32_bf16(af[mt], bfm[nt], acc[mt][nt], 0, 0, 0);
    __builtin_amdgcn_s_setprio(0);
    char* tmp = b0; b0 = b1; b1 = b2; b2 = tmp;
  }
  if constexpr (MODE == 1 || MODE == 2){
    bf16* dst = (bf16*)Cout;
    constexpr int NH = (MODE == 1) ? 16 : 4;
    constexpr float SC = (MODE == 1) ? 0.18033688011112042f : 1.0f;  // 0.125*log2e
    #pragma unroll
    for (int mt = 0; mt < 4; mt++){
      #pragma unroll
      for (int nt = 0; nt < 2; nt++){
        const int col = n0 + wn*64 + nt*16 + lr;
        const int d = col & 63;
        const int hh = col >> 6;
        const float b1v = bias[col], b2v = bias[col + 32];
        #pragma unroll
        for (int i = 0; i < 4; i++){
          const int m = m0 + wm*64 + mt*16 + lg*4 + i;
          const int s = m & 2047, bb = m >> 11;
          const float cs = tab[(s*32 + d)*2], sn = tab[(s*32 + d)*2 + 1];
          const float x1 = acc[mt][nt][i] + b1v;
          const float x2 = acc[mt][nt+2][i] + b2v;
          const size_t o = ((size_t)(bb*NH + hh) * 2048 + s) * 64 + d;
          dst[o]      = __float2bfloat16((x1*cs - x2*sn) * SC);
          dst[o + 32] = __float2bfloat16((x2*cs + x1*sn) * SC);
        }
      }
    }
  } else {  // MODE 3: V^T
    bf16* dst = (bf16*)Cout;
    #pragma unroll
    for (int mt = 0; mt < 4; mt++){
      #pragma unroll
      for (int nt = 0; nt < 4; nt++){
        const int col = n0 + wn*64 + nt*16 + lr;
        const int kv = col >> 6, d = col & 63;
        const float bv = bias[col];
        #pragma unroll
        for (int i = 0; i < 4; i++){
          const int m = m0 + wm*64 + mt*16 + lg*4 + i;
          const int s = m & 2047, bb = m >> 11;
          dst[((size_t)(bb*4 + kv) * 64 + d) * 2048 + s] = __float2bfloat16(acc[mt][nt][i] + bv);
        }
      }
    }
  }
}

// Merged QKV projection: x 0-7 Q tiles, 8-9 K tiles, 10-11 V tiles.
__global__ __launch_bounds__(256, 2) void gemm_qkv_kernel(
    bf16* Qa, bf16* Ka, bf16* Va,
    const float* query, const float* key, const float* value, const bf16* cw,
    const float* bq, const float* bk, const float* bv, const float* tab){
  __shared__ char lds[3 * 24576];
  const int x = blockIdx.x;
  if (x < 8)
    gemm_f32a<1>(lds, Qa, query, cw + CW_WQ, bq, tab, x,    1024, 1024);
  else if (x < 10)
    gemm_f32a<2>(lds, Ka, key,   cw + CW_WK, bk, tab, x-8,  256, 1024);
  else
    gemm_f32a<3>(lds, Va, value, cw + CW_WV, bv, tab, x-10, 256, 1024);
}

// ---------------- GEMM bf16-A (output projection), unchanged structure ----
__device__ __forceinline__ void gemm_bt_out(
    short* lds, float* __restrict__ C,
    const bf16* __restrict__ A, const bf16* __restrict__ B,
    const float* __restrict__ bias, int ntile, int N, int K)
{
  const int NK = K >> 5;
  const int n0 = ntile * 128, m0 = blockIdx.y * 128;
  const int tid = threadIdx.x, w = tid >> 6, lane = tid & 63;
  const int wm = w >> 1, wn = w & 1, lr = lane & 15, lg = lane >> 4;
  const int r0 = w*32 + (lane >> 2), r1 = r0 + 16;
  const int c0 = ((lane & 3) ^ ((r0 >> 1) & 3)) * 8;
  const int c1 = ((lane & 3) ^ ((r1 >> 1) & 3)) * 8;
  const bf16* A0 = A + (size_t)(m0 + r0) * K + c0;
  const bf16* A1 = A + (size_t)(m0 + r1) * K + c1;
  const bf16* B0 = B + (size_t)(n0 + r0) * K + c0;
  const bf16* B1 = B + (size_t)(n0 + r1) * K + c1;
  const int ldsW = (w*32) * 32;
  int offA[4], offB[4];
  #pragma unroll
  for (int i = 0; i < 4; i++){
    const int ra = wm*64 + i*16 + lr;
    offA[i] = ra*64 + ((lg ^ ((ra >> 1) & 3)) * 16);
    const int rb = wn*64 + i*16 + lr;
    offB[i] = rb*64 + ((lg ^ ((rb >> 1) & 3)) * 16);
  }
  auto stage = [&](int t){
    short* bufA = lds + (t & 3) * 8192;
    short* bufB = bufA + 4096;
    gload16(A0 + t*32, bufA + ldsW);
    gload16(A1 + t*32, bufA + ldsW + 512);
    gload16(B0 + t*32, bufB + ldsW);
    gload16(B1 + t*32, bufB + ldsW + 512);
  };
  f32x4 acc[4][4] = {};
  stage(0); stage(1);
  for (int t = 0; t < NK; t++){
    if (t + 2 < NK){ stage(t + 2); vm_barrier<8>(); }
    else if (t + 1 < NK){ vm_barrier<4>(); }
    else { vm_barrier<0>(); }
    const char* bufA = (const char*)(lds + (t & 3) * 8192);
    const char* bufB = bufA + 8192;
    short8 af[4], bfm[4];
    #pragma unroll
    for (int mt = 0; mt < 4; mt++) af[mt]  = *(const short8*)(bufA + offA[mt]);
    #pragma unroll
    for (int nt = 0; nt < 4; nt++) bfm[nt] = *(const short8*)(bufB + offB[nt]);
    __builtin_amdgcn_s_setprio(1);
    #pragma unroll
    for (int mt = 0; mt < 4; mt++)
      #pragma unroll
      for (int nt = 0; nt < 4; nt++)
        acc[mt][nt] = __builtin_amdgcn_mfma_f32_16x16x32_bf16(af[mt], bfm[nt], acc[mt][nt], 0, 0, 0);
    __builtin_amdgcn_s_setprio(0);
  }
  #pragma unroll
  for (int mt = 0; mt < 4; mt++){
    #pragma unroll
    for (int nt = 0; nt < 4; nt++){
      const int col = n0 + wn*64 + nt*16 + lr;
      const float bv = bias[col];
      const int rbase = m0 + wm*64 + mt*16 + lg*4;
      #pragma unroll
      for (int i = 0; i < 4; i++)
        C[(size_t)(rbase + i) * N + col] = acc[mt][nt][i] + bv;
    }
  }
}

__global__ __launch_bounds__(256, 2) void gemm_out_kernel(
    float* C, const bf16* ctx, const bf16* cw, const float* bo){
  __shared__ short lds[4 * 8192];
  gemm_bt_out(lds, C, ctx, cw + CW_WO, bo, blockIdx.x, 1024, 1024);
}

// Flash attention v12: round-12 structure + XCD-aware block swizzle so all
// 16 q-blocks of one bh (sharing 512KB K/V) land on ONE XCD -> L2-resident.
__global__ __launch_bounds__(256, 2) void attn_kernel(
    bf16* __restrict__ ctx, const bf16* __restrict__ Qa,
    const bf16* __restrict__ Ka, const bf16* __restrict__ Vt)
{
  __shared__ short Klds[4][64 * 64];
  __shared__ short Vlds[4][64 * 64];
  // XCD swizzle: pid%8 selects XCD (round-robin dispatch); make bh-group a
  // function of pid%8 so each XCD owns one (b,kvh) K/V slice.
  const int pid = blockIdx.y * 16 + blockIdx.x;
  const int bh = (pid & 7) * 4 + ((pid >> 3) & 3);
  const int q0 = (pid >> 5) * 128;
  const int b = bh >> 4, h = bh & 15, kvh = h >> 2;
  const int tid = threadIdx.x, w = tid >> 6, lane = tid & 63;
  const int lr = lane & 15, lg = lane >> 4;
  const bf16* Qbase = Qa + (size_t)bh * 2048 * 64;
  const bf16* Kbase = Ka + (size_t)(b*4 + kvh) * 2048 * 64;
  const bf16* Vbase = Vt + (size_t)(b*4 + kvh) * 64 * 2048;

  short8 qf[2][2];
  #pragma unroll
  for (int qt = 0; qt < 2; qt++){
    qf[qt][0] = load8(Qbase + (size_t)(q0 + w*32 + qt*16 + lr) * 64 + lg*8);
    qf[qt][1] = load8(Qbase + (size_t)(q0 + w*32 + qt*16 + lr) * 64 + 32 + lg*8);
  }

  // hoisted per-lane swizzled LDS read offsets (bytes); row&7 == lr&7
  const int xsw = (lr & 7) << 4;
  const int koff0 = lr*128 + ((lg*16) ^ xsw);
  const int koff1 = lr*128 + ((64 + lg*16) ^ xsw);
  int voff[2][2];
  #pragma unroll
  for (int kkA = 0; kkA < 2; kkA++)
    #pragma unroll
    for (int hh = 0; hh < 2; hh++)
      voff[kkA][hh] = lr*128 + ((kkA*64 + lg*8 + hh*32) ^ xsw);

  // staging: wave w covers rows w*16..w*16+15 (two 8-row DMA chunks).
  const int l8 = lane >> 3;
  const int ch = (lane & 7) ^ l8;
  const bf16* kSrc = Kbase + (size_t)(w*16 + l8) * 64 + ch*8;
  const bf16* vSrc = Vbase + (size_t)(w*16 + l8) * 2048 + ch*8;
  auto stage = [&](int bi, int t){
    short* Kd = &Klds[bi][(w*16) * 64];
    short* Vd = &Vlds[bi][(w*16) * 64];
    const bf16* ks = kSrc + (size_t)t * 64 * 64;
    const bf16* vs = vSrc + t * 64;
    gload16(ks,           Kd);
    gload16(ks + 8*64,    Kd + 8*64);
    gload16(vs,           Vd);
    gload16(vs + 8*2048,  Vd + 8*64);
  };

  float mrow[2] = {-1e30f, -1e30f};
  f32x4 o[2][4] = {};
  f32x4 acc_l[2] = {};
  short8 ones;
  #pragma unroll
  for (int j = 0; j < 4; j++) reinterpret_cast<unsigned*>(&ones)[j] = 0x3F803F80u;

  auto qk = [&](const char* Kc, f32x4 (&st)[4][2]){
    __builtin_amdgcn_s_setprio(1);
    #pragma unroll
    for (int mt = 0; mt < 4; mt++){
      short8 kf0 = *reinterpret_cast<const short8*>(Kc + mt*2048 + koff0);
      short8 kf1 = *reinterpret_cast<const short8*>(Kc + mt*2048 + koff1);
      #pragma unroll
      for (int qt = 0; qt < 2; qt++){
        st[mt][qt] = __builtin_amdgcn_mfma_f32_16x16x32_bf16(kf0, qf[qt][0], (f32x4){0.f,0.f,0.f,0.f}, 0, 0, 0);
        st[mt][qt] = __builtin_amdgcn_mfma_f32_16x16x32_bf16(kf1, qf[qt][1], st[mt][qt], 0, 0, 0);
      }
    }
    __builtin_amdgcn_s_setprio(0);
  };

  auto softmax_pv = [&](f32x4 (&st)[4][2], const char* Vc){
    short8 pf[2][2];
    #pragma unroll
    for (int qt = 0; qt < 2; qt++){
      const float m0 = max3f(st[0][qt][0], st[0][qt][1], st[0][qt][2]);
      const float m1 = max3f(st[0][qt][3], st[1][qt][0], st[1][qt][1]);
      const float m2 = max3f(st[1][qt][2], st[1][qt][3], st[2][qt][0]);
      const float m3 = max3f(st[2][qt][1], st[2][qt][2], st[2][qt][3]);
      const float m4 = max3f(st[3][qt][0], st[3][qt][1], st[3][qt][2]);
      float mx = fmaxf(max3f(m0, m1, m2), max3f(m3, m4, st[3][qt][3]));
      if (__any(mx > mrow[qt] + 8.0f)){
        mx = fmaxf(mx, __shfl_xor(mx, 16));
        mx = fmaxf(mx, __shfl_xor(mx, 32));
        const float nm = fmaxf(mrow[qt], mx);
        const float alpha = exp2_fast(mrow[qt] - nm);
        mrow[qt] = nm;
        float ab[4];
        #pragma unroll
        for (int i = 0; i < 4; i++) ab[i] = __shfl(alpha, lg*4 + i);
        #pragma unroll
        for (int dt = 0; dt < 4; dt++)
          #pragma unroll
          for (int i = 0; i < 4; i++)
            o[qt][dt][i] *= ab[i];
        #pragma unroll
        for (int i = 0; i < 4; i++) acc_l[qt][i] *= ab[i];
      }
      unsigned* pw = reinterpret_cast<unsigned*>(&pf[qt][0]);
      #pragma unroll
      for (int j = 0; j < 8; j++){
        const int mt = j >> 1, i0 = (j & 1) * 2;
        const float e0 = exp2_fast(st[mt][qt][i0]     - mrow[qt]);
        const float e1 = exp2_fast(st[mt][qt][i0 + 1] - mrow[qt]);
        pw[j] = cvt_pk_bf16(e0, e1);
      }
    }
    __builtin_amdgcn_s_setprio(1);
    #pragma unroll
    for (int qt = 0; qt < 2; qt++){
      acc_l[qt] = __builtin_amdgcn_mfma_f32_16x16x32_bf16(pf[qt][0], ones, acc_l[qt], 0, 0, 0);
      acc_l[qt] = __builtin_amdgcn_mfma_f32_16x16x32_bf16(pf[qt][1], ones, acc_l[qt], 0, 0, 0);
    }
    #pragma unroll
    for (int dt = 0; dt < 4; dt++){
      #pragma unroll
      for (int kkA = 0; kkA < 2; kkA++){
        short8 vf;
        *reinterpret_cast<short4v*>(&vf) =
            *reinterpret_cast<const short4v*>(Vc + dt*2048 + voff[kkA][0]);
        *reinterpret_cast<short4v*>(reinterpret_cast<short*>(&vf) + 4) =
            *reinterpret_cast<const short4v*>(Vc + dt*2048 + voff[kkA][1]);
        #pragma unroll
        for (int qt = 0; qt < 2; qt++)
          o[qt][dt] = __builtin_amdgcn_mfma_f32_16x16x32_bf16(pf[qt][kkA], vf, o[qt][dt], 0, 0, 0);
      }
    }
    __builtin_amdgcn_s_setprio(0);
  };

  f32x4 stA[4][2], stB[4][2];

  stage(0, 0); stage(1, 1);
  vm_barrier<4>();
  qk((const char*)&Klds[0][0], stA);

  for (int tt = 0; tt < 32; tt += 2){
    if (tt + 2 < 32){ stage((tt+2) & 3, tt+2); vm_barrier<4>(); }
    else vm_barrier<0>();
    qk((const char*)&Klds[(tt+1) & 3][0], stB);
    softmax_pv(stA, (const char*)&Vlds[tt & 3][0]);
    if (tt + 3 < 32){ stage((tt+3) & 3, tt+3); vm_barrier<4>(); }
    else vm_barrier<0>();
    if (tt + 2 < 32) qk((const char*)&Klds[(tt+2) & 3][0], stA);
    softmax_pv(stB, (const char*)&Vlds[(tt+1) & 3][0]);
  }

  #pragma unroll
  for (int qt = 0; qt < 2; qt++){
    float lb[4];
    #pragma unroll
    for (int i = 0; i < 4; i++) lb[i] = 1.0f / acc_l[qt][i];
    #pragma unroll
    for (int dt = 0; dt < 4; dt++){
      #pragma unroll
      for (int i = 0; i < 4; i++){
        const int q = q0 + w*32 + qt*16 + lg*4 + i;
        ctx[(size_t)(b*2048 + q) * 1024 + h*64 + dt*16 + lr] =
            __float2bfloat16(o[qt][dt][i] * lb[i]);
      }
    }
  }
}

extern "C" void kernel_launch(void* const* d_in, const int* in_sizes, int n_in,
                              void* d_out, int out_size, void* d_ws, size_t ws_size,
                              hipStream_t stream)
{
  const float* query = (const float*)d_in[0];
  const float* key   = (const float*)d_in[1];
  const float* value = (const float*)d_in[2];
  const float* Wq = (const float*)d_in[3];
  const float* bq = (const float*)d_in[4];
  const float* Wk = (const float*)d_in[5];
  const float* bk = (const float*)d_in[6];
  const float* Wv = (const float*)d_in[7];
  const float* bv = (const float*)d_in[8];
  const float* Wo = (const float*)d_in[9];
  const float* bo = (const float*)d_in[10];
  float* out = (float*)d_out;

  char* ws = (char*)d_ws;
  size_t off = 0;
  float* tab = (float*)(ws + off); off += (size_t)2048 * 32 * 2 * 4;   // cos/sin
  bf16*  Qa  = (bf16*)(ws + off);  off += (size_t)32 * 2048 * 64 * 2;  // [B*16,S,64]
  bf16*  Ka  = (bf16*)(ws + off);  off += (size_t)8 * 2048 * 64 * 2;   // [B*4,S,64]
  bf16*  Va  = (bf16*)(ws + off);  off += (size_t)8 * 64 * 2048 * 2;   // [B*4,64,S]
  bf16*  ctx = (bf16*)(ws + off);  off += (size_t)2 * 2048 * 1024 * 2; // [B,S,1024]
  bf16*  cw  = (bf16*)(ws + off);  off += (size_t)CW_TOT * 2;          // bf16 weights

  cvt_kernel<<<CW_TOT / 8 / 256, 256, 0, stream>>>(cw, tab, Wq, Wk, Wv, Wo);
  gemm_qkv_kernel<<<dim3(12, 32), 256, 0, stream>>>(Qa, Ka, Va, query, key, value,
                                                    cw, bq, bk, bv, tab);
  attn_kernel<<<dim3(16, 32), 256, 0, stream>>>(ctx, Qa, Ka, Va);
  gemm_out_kernel<<<dim3(8, 32), 256, 0, stream>>>(out, ctx, cw, bo);
}